// Round 13
// baseline (170.696 us; speedup 1.0000x reference)
//
#include <hip/hip_runtime.h>
#include <hip/hip_bf16.h>

typedef __bf16 bf16x8 __attribute__((ext_vector_type(8)));
typedef float f32x4 __attribute__((ext_vector_type(4)));
typedef unsigned short ushort8 __attribute__((ext_vector_type(8)));
typedef unsigned short ushort4v __attribute__((ext_vector_type(4)));

constexpr int M = 128;             // B*T
constexpr int K = 4096;            // IN (= 2^12)
constexpr int N = 11008;           // OUT
constexpr int BN = 64;             // N cols per block
constexpr int BK = 32;             // K per step
constexpr int KSPLIT = 4;
constexpr int KBLK = K / KSPLIT;   // 1024
constexpr int NBX = N / BN;        // 172
constexpr int NBLK = NBX * KSPLIT; // 688
constexpr long long NW = (long long)N * K;
constexpr size_t MN = (size_t)M * N;
constexpr int SCAP = 2048;         // suspects/block cap (expect ~310)

// A-priori delta estimate E|N(0,1)| = sqrt(2/pi). Ternary codes computed with
// DHAT equal codes computed with exact delta for every w with ||w/DHAT|-0.5| >
// BAND, provided |delta/DHAT-1| <= 2*BAND (actual ~1e-4; DEVMAX guards 0.006).
// The 1.5 boundary is inert after clip (both sides -> +-1). Suspects inside the
// band are re-coded exactly in `fixup` and corrected sparsely.
constexpr float DHAT = 0.79788456f;
constexpr float INV_DHAT = 1.0f / DHAT;
constexpr float BAND = 0.004f;
constexpr float DEVMAX = 0.006f;

// ws layout (bytes)
constexpr size_t PART_OFF  = 0;                            // 688 f32 partial |w| sums
constexpr size_t FLAG_OFF  = 4096;                         // u32 fallback flag
constexpr size_t CNT_OFF   = FLAG_OFF + 4;                 // 688 u32 suspect counts
constexpr size_t XBF_OFF   = 8192;                         // X bf16 (1 MB)
constexpr size_t SLIST_OFF = XBF_OFF + (size_t)M * K * 2;  // 688*2048*8 B
constexpr size_t P_OFF     = SLIST_OFF + (size_t)NBLK * SCAP * 8;
constexpr size_t WS_NEED   = P_OFF + KSPLIT * MN * sizeof(float);   // ~35 MB
constexpr size_t WS_MIN    = 8192;

__device__ __forceinline__ unsigned short f2bf_bits(float f) {
    unsigned int u = __builtin_bit_cast(unsigned int, f);
    u += 0x7FFFu + ((u >> 16) & 1u);            // RNE to bf16
    return (unsigned short)(u >> 16);
}
__device__ __forceinline__ float bf_to_f32(unsigned short b) {
    return __builtin_bit_cast(float, ((unsigned int)b) << 16);
}
__device__ __forceinline__ int tern(float w, float inv_d) {
    float q = rintf(w * inv_d);                 // RNE = jnp.round
    q = fminf(1.f, fmaxf(-1.f, q));
    return (int)q;
}
__device__ __forceinline__ float block_delta(const float* partials, int tid) {
    __shared__ float red[4];
    float s = 0.f;
    for (int i = tid; i < NBLK; i += 256) s += partials[i];
#pragma unroll
    for (int off = 32; off > 0; off >>= 1) s += __shfl_down(s, off, 64);
    if ((tid & 63) == 0) red[tid >> 6] = s;
    __syncthreads();
    return (float)((double)((red[0] + red[1]) + (red[2] + red[3])) /
                   (double)NW + 1e-8);
}

// ---- k1: X -> bf16 (tiny) ----
__global__ __launch_bounds__(256) void xcvt(const float* __restrict__ x,
                                            unsigned short* __restrict__ xbf)
{
    const int gtid = blockIdx.x * blockDim.x + threadIdx.x;   // 65536 exact
    const float4* xp = (const float4*)x + (size_t)gtid * 2;
    float4 a = xp[0], b = xp[1];
    ushort8 o;
    o[0] = f2bf_bits(a.x); o[1] = f2bf_bits(a.y);
    o[2] = f2bf_bits(a.z); o[3] = f2bf_bits(a.w);
    o[4] = f2bf_bits(b.x); o[5] = f2bf_bits(b.y);
    o[6] = f2bf_bits(b.z); o[7] = f2bf_bits(b.w);
    *(ushort8*)(xbf + (size_t)gtid * 8) = o;
}

// ---- k2: single-W-pass GEMM with a-priori quantize + |w| partials + suspects ----
// grid (172,4); writes RAW acc (no delta) to p[by]; r11 latency structure.
__global__ __launch_bounds__(256, 4) void bitlinear_gemm(
    const unsigned short* __restrict__ xb, const float* __restrict__ W,
    float* __restrict__ partials, unsigned int* __restrict__ cnt,
    uint2* __restrict__ slist, unsigned int* __restrict__ flag,
    float* __restrict__ pbase)
{
    constexpr int KSTEPS = KBLK / BK;           // 32
    constexpr int LDSW = 40;                    // 32 + 8 pad shorts (80 B rows)
    __shared__ __attribute__((aligned(16))) unsigned short xs[2][M * LDSW];
    __shared__ __attribute__((aligned(16))) unsigned short wsm[2][BN * LDSW];
    __shared__ float red[4];

    const int tid = threadIdx.x;
    const int lane = tid & 63;
    const int wid = tid >> 6;
    const int wm = wid >> 1;
    const int wn = wid & 1;
    const int cgrp = lane >> 4;
    const int l15 = lane & 15;
    const int n0 = blockIdx.x * BN;
    const int kk0 = blockIdx.y * KBLK;
    const int bid = blockIdx.y * NBX + blockIdx.x;
    const int K4 = K / 4;
    const float4* w4p = (const float4*)W;
    uint2* mylist = slist + (size_t)bid * SCAP;

    ushort8 xrA[2], xrB[2];
    float4 wrA[2], wrB[2];
    float sabs = 0.f;

    auto issue_set = [&](int t, ushort8 (&xr)[2], float4 (&wr)[2]) {
#pragma unroll
        for (int i = 0; i < 2; ++i) {           // X: 512 slots, row=j>>2, ch=j&3
            const int j = tid + i * 256;
            xr[i] = *(const ushort8*)(xb + (size_t)(j >> 2) * K + kk0 + t * BK + (j & 3) * 8);
        }
#pragma unroll
        for (int i = 0; i < 2; ++i) {           // W: 512 slots, row=j>>3, q4=j&7
            const int j = tid + i * 256;
            wr[i] = w4p[(size_t)(n0 + (j >> 3)) * K4 + (kk0 + t * BK) / 4 + (j & 7)];
        }
    };

    auto stage_set = [&](int buf, int t, ushort8 (&xr)[2], float4 (&wr)[2]) {
#pragma unroll
        for (int i = 0; i < 2; ++i) {
            const int j = tid + i * 256;
            *(ushort8*)&xs[buf][(j >> 2) * LDSW + (j & 3) * 8] = xr[i];
        }
#pragma unroll
        for (int i = 0; i < 2; ++i) {
            const int j = tid + i * 256;
            const int row = j >> 3, q4 = j & 7;
            float wf[4] = {wr[i].x, wr[i].y, wr[i].z, wr[i].w};
            ushort4v wq;
#pragma unroll
            for (int e = 0; e < 4; ++e) {
                const float r = wf[e] * INV_DHAT;
                float qv = rintf(r);
                qv = fminf(1.f, fmaxf(-1.f, qv));
                wq[e] = f2bf_bits(qv);          // exact bf16 {-1,0,+1}
                sabs += fabsf(wf[e]);
                if (fabsf(fabsf(r) - 0.5f) < BAND) {   // boundary suspect (rare)
                    unsigned int slot = atomicAdd(cnt + bid, 1u);
                    if (slot < SCAP) {
                        unsigned int idx = ((unsigned int)(n0 + row) << 12) |
                                           (unsigned int)(kk0 + t * BK + q4 * 4 + e);
                        mylist[slot] = make_uint2(idx, __float_as_uint(wf[e]));
                    } else {
                        atomicOr(flag, 1u);
                    }
                }
            }
            *(ushort4v*)&wsm[buf][row * LDSW + q4 * 4] = wq;
        }
    };

    f32x4 acc[4][2] = {};

    auto compute = [&](int buf) {
        const unsigned short* xcur = xs[buf];
        const unsigned short* wcur = wsm[buf];
        bf16x8 afr[4], bfr[2];
#pragma unroll
        for (int f = 0; f < 4; ++f)
            afr[f] = *(const bf16x8*)&xcur[(wm * 64 + f * 16 + l15) * LDSW + cgrp * 8];
#pragma unroll
        for (int g = 0; g < 2; ++g)
            bfr[g] = *(const bf16x8*)&wcur[(wn * 32 + g * 16 + l15) * LDSW + cgrp * 8];
#pragma unroll
        for (int f = 0; f < 4; ++f)
#pragma unroll
            for (int g = 0; g < 2; ++g)
                acc[f][g] = __builtin_amdgcn_mfma_f32_16x16x32_bf16(
                    afr[f], bfr[g], acc[f][g], 0, 0, 0);
    };

    issue_set(0, xrA, wrA);
    issue_set(1, xrB, wrB);

    for (int t = 0; t < KSTEPS; t += 2) {
        stage_set(0, t, xrA, wrA);
        if (t + 2 < KSTEPS) issue_set(t + 2, xrA, wrA);
        __syncthreads();
        compute(0);
        stage_set(1, t + 1, xrB, wrB);
        if (t + 3 < KSTEPS) issue_set(t + 3, xrB, wrB);
        __syncthreads();
        compute(1);
    }

    // |w| partial for this block's disjoint W tile
#pragma unroll
    for (int off = 32; off > 0; off >>= 1) sabs += __shfl_down(sabs, off, 64);
    if (lane == 0) red[wid] = sabs;
    __syncthreads();
    if (tid == 0) partials[bid] = (red[0] + red[1]) + (red[2] + red[3]);

    // epilogue: RAW acc (delta applied in combine). D layout validated.
    float* dst = pbase + (size_t)blockIdx.y * MN;
#pragma unroll
    for (int f = 0; f < 4; ++f) {
        const int mrow = wm * 64 + f * 16 + cgrp * 4;
#pragma unroll
        for (int g = 0; g < 2; ++g) {
            const int ocol = n0 + wn * 32 + g * 16 + l15;
#pragma unroll
            for (int r = 0; r < 4; ++r)
                dst[(size_t)(mrow + r) * N + ocol] = acc[f][g][r];
        }
    }
}

// ---- k3 combine: out = delta * sum_y p_y + bias ----
__global__ __launch_bounds__(256) void combine(const float* __restrict__ p,
                                               const float* __restrict__ partials,
                                               const float* __restrict__ bias,
                                               float4* __restrict__ out)
{
    const float delta = block_delta(partials, threadIdx.x);
    const int i4 = blockIdx.x * blockDim.x + threadIdx.x;
    constexpr int N4 = N / 4;
    if (i4 >= (int)(MN / 4)) return;
    const float4 b = *(const float4*)(bias + (i4 % N4) * 4);
    float4 s = {};
#pragma unroll
    for (int y = 0; y < KSPLIT; ++y) {
        float4 v = ((const float4*)(p + y * MN))[i4];
        s.x += v.x; s.y += v.y; s.z += v.z; s.w += v.w;
    }
    float4 o;
    o.x = fmaf(delta, s.x, b.x); o.y = fmaf(delta, s.y, b.y);
    o.z = fmaf(delta, s.z, b.z); o.w = fmaf(delta, s.w, b.w);
    out[i4] = o;
}

// ---- k4 fixup: sparse exact correction for boundary suspects ----
// grid (172,4) matching gemm blocks. Normal: walk this block's suspect list,
// apply delta*(q(delta)-q(DHAT))*x to out columns (~1-2K flips total).
// Fallback (flag or dev too large): exact rescan of this block's W tile.
__global__ __launch_bounds__(256) void fixup(
    const float* __restrict__ W, const unsigned short* __restrict__ xbf,
    const float* __restrict__ partials, const unsigned int* __restrict__ cnt,
    const uint2* __restrict__ slist, const unsigned int* __restrict__ flag,
    float* __restrict__ out)
{
    const int tid = threadIdx.x;
    const float delta = block_delta(partials, tid);
    const float inv_delta = 1.0f / delta;
    const int bid = blockIdx.y * NBX + blockIdx.x;
    const bool bad = (*flag != 0u) || (fabsf(delta * INV_DHAT - 1.f) > DEVMAX);

    if (!bad) {
        const int cb = (int)min(cnt[bid], (unsigned int)SCAP);
        const uint2* mylist = slist + (size_t)bid * SCAP;
        for (int si = 0; si < cb; ++si) {
            const uint2 e = mylist[si];
            const float w = __uint_as_float(e.y);
            const int dq = tern(w, inv_delta) - tern(w, INV_DHAT);
            if (dq == 0) continue;              // uniform branch
            const unsigned int n = e.x >> 12, k = e.x & 4095u;
            const float corr = delta * (float)dq;
            if (tid < M)
                atomicAdd(&out[(size_t)tid * N + n],
                          corr * bf_to_f32(xbf[(size_t)tid * K + k]));
        }
    } else {                                    // pathological input: exact rescan
        const int n0 = blockIdx.x * BN, kk0 = blockIdx.y * KBLK;
        for (int r = 0; r < BN; ++r) {
            for (int kk = tid; kk < KBLK; kk += 256) {
                const float w = W[(size_t)(n0 + r) * K + kk0 + kk];
                const int dq = tern(w, inv_delta) - tern(w, INV_DHAT);
                if (dq == 0) continue;
                const float corr = delta * (float)dq;
                for (int m = 0; m < M; ++m)
                    atomicAdd(&out[(size_t)m * N + n0 + r],
                              corr * bf_to_f32(xbf[(size_t)m * K + kk0 + kk]));
            }
        }
    }
}

// ---- small-ws fallback: r11's passing direct path (2 full W passes) ----
__global__ __launch_bounds__(256) void absmean_direct(const float* __restrict__ w,
                                                      float* __restrict__ partials)
{
    const int gtid = blockIdx.x * blockDim.x + threadIdx.x;
    const int n4 = (int)(NW / 4);
    const float4* w4 = (const float4*)w;
    float s0 = 0.f, s1 = 0.f, s2 = 0.f, s3 = 0.f;
    for (int i = gtid; i < n4; i += gridDim.x * blockDim.x) {
        float4 v = w4[i];
        s0 += fabsf(v.x); s1 += fabsf(v.y); s2 += fabsf(v.z); s3 += fabsf(v.w);
    }
    float s = (s0 + s1) + (s2 + s3);
#pragma unroll
    for (int off = 32; off > 0; off >>= 1) s += __shfl_down(s, off, 64);
    __shared__ float red[4];
    if ((threadIdx.x & 63) == 0) red[threadIdx.x >> 6] = s;
    __syncthreads();
    if (threadIdx.x == 0)
        partials[blockIdx.x] = (red[0] + red[1]) + (red[2] + red[3]);
}

__global__ __launch_bounds__(256, 4) void gemm_direct(
    const float* __restrict__ X, const float* __restrict__ W,
    const float* __restrict__ bias, const float* __restrict__ partials,
    float* __restrict__ out)
{
    constexpr int KSTEPS = K / BK;
    constexpr int LDSW = 40;
    __shared__ __attribute__((aligned(16))) unsigned short xs[2][M * LDSW];
    __shared__ __attribute__((aligned(16))) unsigned short wsm[2][BN * LDSW];
    __shared__ float red[4];
    const int tid = threadIdx.x, lane = tid & 63, wid = tid >> 6;
    const int wm = wid >> 1, wn = wid & 1, cgrp = lane >> 4, l15 = lane & 15;
    const int n0 = blockIdx.x * BN, K4 = K / 4;
    const float4* x4p = (const float4*)X;
    const float4* w4p = (const float4*)W;
    float4 xfA[4], xfB[4], wrA[2], wrB[2];

    auto issue_set = [&](int t, float4 (&xf)[4], float4 (&wr)[2]) {
#pragma unroll
        for (int i = 0; i < 4; ++i) {
            const int j = tid + i * 256;
            xf[i] = x4p[(size_t)(j >> 3) * K4 + (t * BK) / 4 + (j & 7)];
        }
#pragma unroll
        for (int i = 0; i < 2; ++i) {
            const int j = tid + i * 256;
            wr[i] = w4p[(size_t)(n0 + (j >> 3)) * K4 + (t * BK) / 4 + (j & 7)];
        }
    };

    float ps[8];
#pragma unroll
    for (int i = 0; i < 8; ++i) ps[i] = partials[tid + i * 256];
    issue_set(0, xfA, wrA);
    issue_set(1, xfB, wrB);
    float s = 0.f;
#pragma unroll
    for (int i = 0; i < 8; ++i) s += ps[i];
#pragma unroll
    for (int off = 32; off > 0; off >>= 1) s += __shfl_down(s, off, 64);
    if (lane == 0) red[wid] = s;
    __syncthreads();
    const float delta =
        (float)((double)((red[0] + red[1]) + (red[2] + red[3])) / (double)NW + 1e-8);
    const float inv_delta = 1.0f / delta;

    auto stage_set = [&](int buf, float4 (&xf)[4], float4 (&wr)[2]) {
#pragma unroll
        for (int i = 0; i < 4; ++i) {
            const int j = tid + i * 256;
            float4 v = xf[i];
            ushort4v o;
            o[0] = f2bf_bits(v.x); o[1] = f2bf_bits(v.y);
            o[2] = f2bf_bits(v.z); o[3] = f2bf_bits(v.w);
            *(ushort4v*)&xs[buf][(j >> 3) * LDSW + (j & 7) * 4] = o;
        }
#pragma unroll
        for (int i = 0; i < 2; ++i) {
            const int j = tid + i * 256;
            float wf[4] = {wr[i].x, wr[i].y, wr[i].z, wr[i].w};
            ushort4v wq;
#pragma unroll
            for (int e = 0; e < 4; ++e)
                wq[e] = f2bf_bits((float)tern(wf[e], inv_delta));
            *(ushort4v*)&wsm[buf][(j >> 3) * LDSW + (j & 7) * 4] = wq;
        }
    };

    f32x4 acc[4][2] = {};
    auto compute = [&](int buf) {
        bf16x8 afr[4], bfr[2];
#pragma unroll
        for (int f = 0; f < 4; ++f)
            afr[f] = *(const bf16x8*)&xs[buf][(wm * 64 + f * 16 + l15) * LDSW + cgrp * 8];
#pragma unroll
        for (int g = 0; g < 2; ++g)
            bfr[g] = *(const bf16x8*)&wsm[buf][(wn * 32 + g * 16 + l15) * LDSW + cgrp * 8];
#pragma unroll
        for (int f = 0; f < 4; ++f)
#pragma unroll
            for (int g = 0; g < 2; ++g)
                acc[f][g] = __builtin_amdgcn_mfma_f32_16x16x32_bf16(
                    afr[f], bfr[g], acc[f][g], 0, 0, 0);
    };

    for (int t = 0; t < KSTEPS; t += 2) {
        stage_set(0, xfA, wrA);
        if (t + 2 < KSTEPS) issue_set(t + 2, xfA, wrA);
        __syncthreads();
        compute(0);
        stage_set(1, xfB, wrB);
        if (t + 3 < KSTEPS) issue_set(t + 3, xfB, wrB);
        __syncthreads();
        compute(1);
    }
#pragma unroll
    for (int f = 0; f < 4; ++f) {
        const int mrow = wm * 64 + f * 16 + cgrp * 4;
#pragma unroll
        for (int g = 0; g < 2; ++g) {
            const int ocol = n0 + wn * 32 + g * 16 + l15;
            const float bv = bias[ocol];
#pragma unroll
            for (int r = 0; r < 4; ++r)
                out[(size_t)(mrow + r) * N + ocol] = delta * acc[f][g][r] + bv;
        }
    }
}

extern "C" void kernel_launch(void* const* d_in, const int* in_sizes, int n_in,
                              void* d_out, int out_size, void* d_ws, size_t ws_size,
                              hipStream_t stream) {
    const float* x = (const float*)d_in[0];
    const float* w = (const float*)d_in[1];
    const float* bias = (const float*)d_in[2];
    float* out = (float*)d_out;
    char* wsb = (char*)d_ws;
    float* partials = (float*)(wsb + PART_OFF);
    unsigned int* flag = (unsigned int*)(wsb + FLAG_OFF);
    unsigned int* cnt = (unsigned int*)(wsb + CNT_OFF);
    unsigned short* xbf = (unsigned short*)(wsb + XBF_OFF);
    uint2* slist = (uint2*)(wsb + SLIST_OFF);
    float* pbase = (float*)(wsb + P_OFF);

    if (ws_size >= WS_NEED) {
        hipMemsetAsync(wsb + FLAG_OFF, 0, 4 + NBLK * 4, stream);
        xcvt<<<M * K / 8 / 256, 256, 0, stream>>>(x, xbf);
        bitlinear_gemm<<<dim3(NBX, KSPLIT), 256, 0, stream>>>(
            xbf, w, partials, cnt, slist, flag, pbase);
        combine<<<(int)(MN / 4) / 256, 256, 0, stream>>>(
            pbase, partials, bias, (float4*)out);
        fixup<<<dim3(NBX, KSPLIT), 256, 0, stream>>>(
            w, xbf, partials, cnt, slist, flag, out);
    } else if (ws_size >= WS_MIN) {
        absmean_direct<<<2048, 256, 0, stream>>>(w, partials);
        gemm_direct<<<NBX, 256, 0, stream>>>(x, w, bias, partials, out);
    }
}

// Round 14
// 72.822 us; speedup vs baseline: 2.3440x; 2.3440x over previous
//
#include <hip/hip_runtime.h>
#include <hip/hip_bf16.h>

typedef __bf16 bf16x8 __attribute__((ext_vector_type(8)));
typedef float f32x4 __attribute__((ext_vector_type(4)));
typedef unsigned short ushort8 __attribute__((ext_vector_type(8)));
typedef unsigned short ushort4v __attribute__((ext_vector_type(4)));

constexpr int M = 128;             // B*T
constexpr int K = 4096;            // IN (= 2^12)
constexpr int N = 11008;           // OUT
constexpr int BN = 64;             // N cols per block
constexpr int BK = 32;             // K per step
constexpr int KSPLIT = 4;
constexpr int KBLK = K / KSPLIT;   // 1024
constexpr int NBX = N / BN;        // 172
constexpr int NBLK = NBX * KSPLIT; // 688
constexpr long long NW = (long long)N * K;
constexpr size_t MN = (size_t)M * N;
constexpr int SCAP = 512;          // suspects/block cap (expect ~15)

// A-priori delta estimate E|N(0,1)| = sqrt(2/pi). Ternary codes computed with
// DHAT equal codes computed with exact delta for every w with ||w/DHAT|-0.5| >=
// BAND, provided |delta/DHAT-1| <= 2*BAND (boundary shift = 0.5*dev < BAND).
// Actual dev ~1.1e-4 (std of mean of 45M half-normals); DEVMAX=3.5e-4 guards
// with deterministic full-rescan fallback. Boundaries at +-1.5, +-2.5, ... are
// inert after the clip (both sides -> +-1). Only +-0.5 matters.
constexpr float DHAT = 0.79788456f;
constexpr float INV_DHAT = 1.0f / DHAT;
constexpr float BAND = 2e-4f;
constexpr float DEVMAX = 3.5e-4f;

// ws layout (bytes)
constexpr size_t PART_OFF  = 0;                            // 688 f32 partial |w| sums
constexpr size_t FLAG_OFF  = 4096;                         // u32 fallback flag
constexpr size_t CNT_OFF   = FLAG_OFF + 4;                 // 688 u32 suspect counts
constexpr size_t XBF_OFF   = 8192;                         // X bf16 (1 MB)
constexpr size_t SLIST_OFF = XBF_OFF + (size_t)M * K * 2;  // 688*512*8 B
constexpr size_t P_OFF     = SLIST_OFF + (size_t)NBLK * SCAP * 8;
constexpr size_t WS_NEED   = P_OFF + KSPLIT * MN * sizeof(float);   // ~26 MB
constexpr size_t WS_MIN    = 8192;

__device__ __forceinline__ unsigned short f2bf_bits(float f) {
    unsigned int u = __builtin_bit_cast(unsigned int, f);
    u += 0x7FFFu + ((u >> 16) & 1u);            // RNE to bf16
    return (unsigned short)(u >> 16);
}
__device__ __forceinline__ float bf_to_f32(unsigned short b) {
    return __builtin_bit_cast(float, ((unsigned int)b) << 16);
}
__device__ __forceinline__ int tern(float w, float inv_d) {
    float q = rintf(w * inv_d);                 // RNE = jnp.round
    q = fminf(1.f, fmaxf(-1.f, q));
    return (int)q;
}
__device__ __forceinline__ float block_delta(const float* partials, int tid) {
    __shared__ float red[4];
    float s = 0.f;
    for (int i = tid; i < NBLK; i += 256) s += partials[i];
#pragma unroll
    for (int off = 32; off > 0; off >>= 1) s += __shfl_down(s, off, 64);
    if ((tid & 63) == 0) red[tid >> 6] = s;
    __syncthreads();
    return (float)((double)((red[0] + red[1]) + (red[2] + red[3])) /
                   (double)NW + 1e-8);
}

// ---- k1: X -> bf16 (tiny) ----
__global__ __launch_bounds__(256) void xcvt(const float* __restrict__ x,
                                            unsigned short* __restrict__ xbf)
{
    const int gtid = blockIdx.x * blockDim.x + threadIdx.x;   // 65536 exact
    const float4* xp = (const float4*)x + (size_t)gtid * 2;
    float4 a = xp[0], b = xp[1];
    ushort8 o;
    o[0] = f2bf_bits(a.x); o[1] = f2bf_bits(a.y);
    o[2] = f2bf_bits(a.z); o[3] = f2bf_bits(a.w);
    o[4] = f2bf_bits(b.x); o[5] = f2bf_bits(b.y);
    o[6] = f2bf_bits(b.z); o[7] = f2bf_bits(b.w);
    *(ushort8*)(xbf + (size_t)gtid * 8) = o;
}

// ---- k2: single-W-pass GEMM, a-priori quantize; r11 hot loop preserved ----
// Suspect capture is branch-free mask + ONE rare branch (~0.1% of threads)
// placed AFTER the LDS store — no per-element atomics in the pipeline (r13 bug).
__global__ __launch_bounds__(256, 4) void bitlinear_gemm(
    const unsigned short* __restrict__ xb, const float* __restrict__ W,
    float* __restrict__ partials, unsigned int* __restrict__ cnt,
    uint2* __restrict__ slist, unsigned int* __restrict__ flag,
    float* __restrict__ pbase)
{
    constexpr int KSTEPS = KBLK / BK;           // 32
    constexpr int LDSW = 40;                    // 32 + 8 pad shorts (80 B rows)
    __shared__ __attribute__((aligned(16))) unsigned short xs[2][M * LDSW];
    __shared__ __attribute__((aligned(16))) unsigned short wsm[2][BN * LDSW];
    __shared__ float red[4];

    const int tid = threadIdx.x;
    const int lane = tid & 63;
    const int wid = tid >> 6;
    const int wm = wid >> 1;
    const int wn = wid & 1;
    const int cgrp = lane >> 4;
    const int l15 = lane & 15;
    const int n0 = blockIdx.x * BN;
    const int kk0 = blockIdx.y * KBLK;
    const int bid = blockIdx.y * NBX + blockIdx.x;
    const int K4 = K / 4;
    const float4* w4p = (const float4*)W;
    uint2* mylist = slist + (size_t)bid * SCAP;

    ushort8 xrA[2], xrB[2];
    float4 wrA[2], wrB[2];
    float sabs = 0.f;

    auto issue_set = [&](int t, ushort8 (&xr)[2], float4 (&wr)[2]) {
#pragma unroll
        for (int i = 0; i < 2; ++i) {           // X: 512 slots, row=j>>2, ch=j&3
            const int j = tid + i * 256;
            xr[i] = *(const ushort8*)(xb + (size_t)(j >> 2) * K + kk0 + t * BK + (j & 3) * 8);
        }
#pragma unroll
        for (int i = 0; i < 2; ++i) {           // W: 512 slots, row=j>>3, q4=j&7
            const int j = tid + i * 256;
            wr[i] = w4p[(size_t)(n0 + (j >> 3)) * K4 + (kk0 + t * BK) / 4 + (j & 7)];
        }
    };

    auto stage_set = [&](int buf, int t, ushort8 (&xr)[2], float4 (&wr)[2]) {
#pragma unroll
        for (int i = 0; i < 2; ++i) {
            const int j = tid + i * 256;
            *(ushort8*)&xs[buf][(j >> 2) * LDSW + (j & 3) * 8] = xr[i];
        }
#pragma unroll
        for (int i = 0; i < 2; ++i) {
            const int j = tid + i * 256;
            const int row = j >> 3, q4 = j & 7;
            float wf[4] = {wr[i].x, wr[i].y, wr[i].z, wr[i].w};
            ushort4v wq;
            unsigned int msk = 0u;
#pragma unroll
            for (int e = 0; e < 4; ++e) {
                const float r = wf[e] * INV_DHAT;
                float qv = rintf(r);
                qv = fminf(1.f, fmaxf(-1.f, qv));
                wq[e] = f2bf_bits(qv);          // exact bf16 {-1,0,+1}
                sabs += fabsf(wf[e]);
                msk |= (fabsf(fabsf(r) - 0.5f) < BAND) ? (1u << e) : 0u;
            }
            *(ushort4v*)&wsm[buf][row * LDSW + q4 * 4] = wq;
            if (msk) {                          // rare: ~0.1% of threads/stage
#pragma unroll
                for (int e = 0; e < 4; ++e) {
                    if (msk & (1u << e)) {
                        unsigned int slot = atomicAdd(cnt + bid, 1u);
                        if (slot < SCAP) {
                            unsigned int idx = ((unsigned int)(n0 + row) << 12) |
                                               (unsigned int)(kk0 + t * BK + q4 * 4 + e);
                            mylist[slot] = make_uint2(idx, __float_as_uint(wf[e]));
                        } else {
                            atomicOr(flag, 1u);
                        }
                    }
                }
            }
        }
    };

    f32x4 acc[4][2] = {};

    auto compute = [&](int buf) {
        const unsigned short* xcur = xs[buf];
        const unsigned short* wcur = wsm[buf];
        bf16x8 afr[4], bfr[2];
#pragma unroll
        for (int f = 0; f < 4; ++f)
            afr[f] = *(const bf16x8*)&xcur[(wm * 64 + f * 16 + l15) * LDSW + cgrp * 8];
#pragma unroll
        for (int g = 0; g < 2; ++g)
            bfr[g] = *(const bf16x8*)&wcur[(wn * 32 + g * 16 + l15) * LDSW + cgrp * 8];
#pragma unroll
        for (int f = 0; f < 4; ++f)
#pragma unroll
            for (int g = 0; g < 2; ++g)
                acc[f][g] = __builtin_amdgcn_mfma_f32_16x16x32_bf16(
                    afr[f], bfr[g], acc[f][g], 0, 0, 0);
    };

    issue_set(0, xrA, wrA);
    issue_set(1, xrB, wrB);

    for (int t = 0; t < KSTEPS; t += 2) {
        stage_set(0, t, xrA, wrA);
        if (t + 2 < KSTEPS) issue_set(t + 2, xrA, wrA);
        __syncthreads();
        compute(0);
        stage_set(1, t + 1, xrB, wrB);
        if (t + 3 < KSTEPS) issue_set(t + 3, xrB, wrB);
        __syncthreads();
        compute(1);
    }

    // |w| partial for this block's disjoint W tile
#pragma unroll
    for (int off = 32; off > 0; off >>= 1) sabs += __shfl_down(sabs, off, 64);
    if (lane == 0) red[wid] = sabs;
    __syncthreads();
    if (tid == 0) partials[bid] = (red[0] + red[1]) + (red[2] + red[3]);

    // epilogue: RAW acc (delta applied in combine). D layout validated.
    float* dst = pbase + (size_t)blockIdx.y * MN;
#pragma unroll
    for (int f = 0; f < 4; ++f) {
        const int mrow = wm * 64 + f * 16 + cgrp * 4;
#pragma unroll
        for (int g = 0; g < 2; ++g) {
            const int ocol = n0 + wn * 32 + g * 16 + l15;
#pragma unroll
            for (int r = 0; r < 4; ++r)
                dst[(size_t)(mrow + r) * N + ocol] = acc[f][g][r];
        }
    }
}

// ---- k3 combine: out = delta * sum_y p_y + bias ----
__global__ __launch_bounds__(256) void combine(const float* __restrict__ p,
                                               const float* __restrict__ partials,
                                               const float* __restrict__ bias,
                                               float4* __restrict__ out)
{
    const float delta = block_delta(partials, threadIdx.x);
    const int i4 = blockIdx.x * blockDim.x + threadIdx.x;
    constexpr int N4 = N / 4;
    if (i4 >= (int)(MN / 4)) return;
    const float4 b = *(const float4*)(bias + (i4 % N4) * 4);
    float4 s = {};
#pragma unroll
    for (int y = 0; y < KSPLIT; ++y) {
        float4 v = ((const float4*)(p + y * MN))[i4];
        s.x += v.x; s.y += v.y; s.z += v.z; s.w += v.w;
    }
    float4 o;
    o.x = fmaf(delta, s.x, b.x); o.y = fmaf(delta, s.y, b.y);
    o.z = fmaf(delta, s.z, b.z); o.w = fmaf(delta, s.w, b.w);
    out[i4] = o;
}

// ---- k4 fixup: sparse exact correction for boundary suspects ----
__global__ __launch_bounds__(256) void fixup(
    const float* __restrict__ W, const unsigned short* __restrict__ xbf,
    const float* __restrict__ partials, const unsigned int* __restrict__ cnt,
    const uint2* __restrict__ slist, const unsigned int* __restrict__ flag,
    float* __restrict__ out)
{
    const int tid = threadIdx.x;
    const float delta = block_delta(partials, tid);
    const float inv_delta = 1.0f / delta;
    const int bid = blockIdx.y * NBX + blockIdx.x;
    const bool bad = (*flag != 0u) || (fabsf(delta * INV_DHAT - 1.f) > DEVMAX);

    if (!bad) {
        const int cb = (int)min(cnt[bid], (unsigned int)SCAP);
        const uint2* mylist = slist + (size_t)bid * SCAP;
        for (int si = 0; si < cb; ++si) {
            const uint2 e = mylist[si];
            const float w = __uint_as_float(e.y);
            const int dq = tern(w, inv_delta) - tern(w, INV_DHAT);
            if (dq == 0) continue;              // uniform branch
            const unsigned int n = e.x >> 12, k = e.x & 4095u;
            const float corr = delta * (float)dq;
            if (tid < M)
                atomicAdd(&out[(size_t)tid * N + n],
                          corr * bf_to_f32(xbf[(size_t)tid * K + k]));
        }
    } else {                                    // pathological input: exact rescan
        const int n0 = blockIdx.x * BN, kk0 = blockIdx.y * KBLK;
        for (int r = 0; r < BN; ++r) {
            for (int kk = tid; kk < KBLK; kk += 256) {
                const float w = W[(size_t)(n0 + r) * K + kk0 + kk];
                const int dq = tern(w, inv_delta) - tern(w, INV_DHAT);
                if (dq == 0) continue;
                const float corr = delta * (float)dq;
                for (int m = 0; m < M; ++m)
                    atomicAdd(&out[(size_t)m * N + n0 + r],
                              corr * bf_to_f32(xbf[(size_t)m * K + kk0 + kk]));
            }
        }
    }
}

// ---- small-ws fallback: r11's passing direct path (2 full W passes) ----
__global__ __launch_bounds__(256) void absmean_direct(const float* __restrict__ w,
                                                      float* __restrict__ partials)
{
    const int gtid = blockIdx.x * blockDim.x + threadIdx.x;
    const int n4 = (int)(NW / 4);
    const float4* w4 = (const float4*)w;
    float s0 = 0.f, s1 = 0.f, s2 = 0.f, s3 = 0.f;
    for (int i = gtid; i < n4; i += gridDim.x * blockDim.x) {
        float4 v = w4[i];
        s0 += fabsf(v.x); s1 += fabsf(v.y); s2 += fabsf(v.z); s3 += fabsf(v.w);
    }
    float s = (s0 + s1) + (s2 + s3);
#pragma unroll
    for (int off = 32; off > 0; off >>= 1) s += __shfl_down(s, off, 64);
    __shared__ float red[4];
    if ((threadIdx.x & 63) == 0) red[threadIdx.x >> 6] = s;
    __syncthreads();
    if (threadIdx.x == 0)
        partials[blockIdx.x] = (red[0] + red[1]) + (red[2] + red[3]);
}

__global__ __launch_bounds__(256, 4) void gemm_direct(
    const float* __restrict__ X, const float* __restrict__ W,
    const float* __restrict__ bias, const float* __restrict__ partials,
    float* __restrict__ out)
{
    constexpr int KSTEPS = K / BK;
    constexpr int LDSW = 40;
    __shared__ __attribute__((aligned(16))) unsigned short xs[2][M * LDSW];
    __shared__ __attribute__((aligned(16))) unsigned short wsm[2][BN * LDSW];
    __shared__ float red[4];
    const int tid = threadIdx.x, lane = tid & 63, wid = tid >> 6;
    const int wm = wid >> 1, wn = wid & 1, cgrp = lane >> 4, l15 = lane & 15;
    const int n0 = blockIdx.x * BN, K4 = K / 4;
    const float4* x4p = (const float4*)X;
    const float4* w4p = (const float4*)W;
    float4 xfA[4], xfB[4], wrA[2], wrB[2];

    auto issue_set = [&](int t, float4 (&xf)[4], float4 (&wr)[2]) {
#pragma unroll
        for (int i = 0; i < 4; ++i) {
            const int j = tid + i * 256;
            xf[i] = x4p[(size_t)(j >> 3) * K4 + (t * BK) / 4 + (j & 7)];
        }
#pragma unroll
        for (int i = 0; i < 2; ++i) {
            const int j = tid + i * 256;
            wr[i] = w4p[(size_t)(n0 + (j >> 3)) * K4 + (t * BK) / 4 + (j & 7)];
        }
    };

    float ps[8];
#pragma unroll
    for (int i = 0; i < 8; ++i) ps[i] = partials[tid + i * 256];
    issue_set(0, xfA, wrA);
    issue_set(1, xfB, wrB);
    float s = 0.f;
#pragma unroll
    for (int i = 0; i < 8; ++i) s += ps[i];
#pragma unroll
    for (int off = 32; off > 0; off >>= 1) s += __shfl_down(s, off, 64);
    if (lane == 0) red[wid] = s;
    __syncthreads();
    const float delta =
        (float)((double)((red[0] + red[1]) + (red[2] + red[3])) / (double)NW + 1e-8);
    const float inv_delta = 1.0f / delta;

    auto stage_set = [&](int buf, float4 (&xf)[4], float4 (&wr)[2]) {
#pragma unroll
        for (int i = 0; i < 4; ++i) {
            const int j = tid + i * 256;
            float4 v = xf[i];
            ushort4v o;
            o[0] = f2bf_bits(v.x); o[1] = f2bf_bits(v.y);
            o[2] = f2bf_bits(v.z); o[3] = f2bf_bits(v.w);
            *(ushort4v*)&xs[buf][(j >> 3) * LDSW + (j & 7) * 4] = o;
        }
#pragma unroll
        for (int i = 0; i < 2; ++i) {
            const int j = tid + i * 256;
            float wf[4] = {wr[i].x, wr[i].y, wr[i].z, wr[i].w};
            ushort4v wq;
#pragma unroll
            for (int e = 0; e < 4; ++e)
                wq[e] = f2bf_bits((float)tern(wf[e], inv_delta));
            *(ushort4v*)&wsm[buf][(j >> 3) * LDSW + (j & 7) * 4] = wq;
        }
    };

    f32x4 acc[4][2] = {};
    auto compute = [&](int buf) {
        bf16x8 afr[4], bfr[2];
#pragma unroll
        for (int f = 0; f < 4; ++f)
            afr[f] = *(const bf16x8*)&xs[buf][(wm * 64 + f * 16 + l15) * LDSW + cgrp * 8];
#pragma unroll
        for (int g = 0; g < 2; ++g)
            bfr[g] = *(const bf16x8*)&wsm[buf][(wn * 32 + g * 16 + l15) * LDSW + cgrp * 8];
#pragma unroll
        for (int f = 0; f < 4; ++f)
#pragma unroll
            for (int g = 0; g < 2; ++g)
                acc[f][g] = __builtin_amdgcn_mfma_f32_16x16x32_bf16(
                    afr[f], bfr[g], acc[f][g], 0, 0, 0);
    };

    for (int t = 0; t < KSTEPS; t += 2) {
        stage_set(0, xfA, wrA);
        if (t + 2 < KSTEPS) issue_set(t + 2, xfA, wrA);
        __syncthreads();
        compute(0);
        stage_set(1, xfB, wrB);
        if (t + 3 < KSTEPS) issue_set(t + 3, xfB, wrB);
        __syncthreads();
        compute(1);
    }
#pragma unroll
    for (int f = 0; f < 4; ++f) {
        const int mrow = wm * 64 + f * 16 + cgrp * 4;
#pragma unroll
        for (int g = 0; g < 2; ++g) {
            const int ocol = n0 + wn * 32 + g * 16 + l15;
            const float bv = bias[ocol];
#pragma unroll
            for (int r = 0; r < 4; ++r)
                out[(size_t)(mrow + r) * N + ocol] = delta * acc[f][g][r] + bv;
        }
    }
}

extern "C" void kernel_launch(void* const* d_in, const int* in_sizes, int n_in,
                              void* d_out, int out_size, void* d_ws, size_t ws_size,
                              hipStream_t stream) {
    const float* x = (const float*)d_in[0];
    const float* w = (const float*)d_in[1];
    const float* bias = (const float*)d_in[2];
    float* out = (float*)d_out;
    char* wsb = (char*)d_ws;
    float* partials = (float*)(wsb + PART_OFF);
    unsigned int* flag = (unsigned int*)(wsb + FLAG_OFF);
    unsigned int* cnt = (unsigned int*)(wsb + CNT_OFF);
    unsigned short* xbf = (unsigned short*)(wsb + XBF_OFF);
    uint2* slist = (uint2*)(wsb + SLIST_OFF);
    float* pbase = (float*)(wsb + P_OFF);

    if (ws_size >= WS_NEED) {
        hipMemsetAsync(wsb + FLAG_OFF, 0, 4 + NBLK * 4, stream);
        xcvt<<<M * K / 8 / 256, 256, 0, stream>>>(x, xbf);
        bitlinear_gemm<<<dim3(NBX, KSPLIT), 256, 0, stream>>>(
            xbf, w, partials, cnt, slist, flag, pbase);
        combine<<<(int)(MN / 4) / 256, 256, 0, stream>>>(
            pbase, partials, bias, (float4*)out);
        fixup<<<dim3(NBX, KSPLIT), 256, 0, stream>>>(
            w, xbf, partials, cnt, slist, flag, out);
    } else if (ws_size >= WS_MIN) {
        absmean_direct<<<2048, 256, 0, stream>>>(w, partials);
        gemm_direct<<<NBX, 256, 0, stream>>>(x, w, bias, partials, out);
    }
}